// Round 6
// baseline (438.475 us; speedup 1.0000x reference)
//
#include <hip/hip_runtime.h>
#include <math.h>

#define BATCH 32768
#define D 512
#define NE 8192
#define NSPLIT 4
#define ESPAN (NE / NSPLIT)   // 2048 entries per split
#define NT 64                 // entries per tile
#define KC 128                // k per chunk (4 chunks over D)
#define NPHASE ((ESPAN / NT) * 4)   // 128
#define MARGIN 1.6e-2f        // ~27 sigma of fp16 distance error (proven rounds 3-5)

typedef float    f32x4 __attribute__((ext_vector_type(4)));
typedef _Float16 f16x8 __attribute__((ext_vector_type(8)));

__device__ __forceinline__ void g2l16(const void* g, void* l) {
    __builtin_amdgcn_global_load_lds((const __attribute__((address_space(1))) void*)g,
                                     (__attribute__((address_space(3))) void*)l, 16, 0, 0);
}
__device__ __forceinline__ unsigned short f2h(float f) {
    union { _Float16 h; unsigned short u; } c; c.h = (_Float16)f; return c.u;
}

// ---------------- fused: codebook norms + fp32->fp16 XOR-pre-swizzled convert ----------------
// 1 wave per codebook row; lane g handles granule g (8 floats).
__global__ void vq_prep(const float* __restrict__ cb, unsigned short* __restrict__ eq,
                        float* __restrict__ norms) {
    const int row = blockIdx.x * 4 + (threadIdx.x >> 6);
    const int g   = threadIdx.x & 63;
    const float4* sp = (const float4*)(cb + (size_t)row * D + g * 8);
    float4 a = sp[0], b = sp[1];
    float s = a.x * a.x + a.y * a.y + a.z * a.z + a.w * a.w
            + b.x * b.x + b.y * b.y + b.z * b.z + b.w * b.w;
    for (int off = 32; off; off >>= 1) s += __shfl_down(s, off);
    if (g == 0) norms[row] = s;
    const int ch = g >> 4;
    const int sl = (g & 15) ^ (row & 15);
    ushort4* dp = (ushort4*)(eq + (size_t)row * D + ch * KC + sl * 8);
    dp[0] = make_ushort4(f2h(a.x), f2h(a.y), f2h(a.z), f2h(a.w));
    dp[1] = make_ushort4(f2h(b.x), f2h(b.y), f2h(b.z), f2h(b.w));
}

// ---------------- fp16 MFMA distance, x-in-registers, per-lane top-2 ----------------
// grid 1024 = 256 rowblocks(128 rows) x 4 splits; block 256 thr (4 waves x 32 rows).
// Per phase: {vmcnt(0)[free] ; barrier ; STAGE(next) ; 1-ahead frag pipeline + MFMA}.
// acc is initialized to -||e||^2/2 so acc_final = e.x - ||e||^2/2 and argmin dist = argmax acc.
struct Frag4 { f16x8 v[4]; };

__global__ __launch_bounds__(256, 2)
void vq_topk2(const float* __restrict__ x, const unsigned short* __restrict__ eq,
              const float* __restrict__ norms, float4* __restrict__ cands) {
    __shared__ char arena[32768];
    unsigned short* es0 = (unsigned short*)arena;            // 16 KB buffer A
    unsigned short* es1 = (unsigned short*)(arena + 16384);  // 16 KB buffer B

    const int t = threadIdx.x;
    const int w = t >> 6, lane = t & 63, l15 = lane & 15, l4 = lane >> 4;
    const int b = blockIdx.x;
    const int xcd = b & 7;                 // blocks sharing an XCD share one eq slice
    const int sp  = xcd >> 1;
    const int rb  = ((b >> 3) << 1) | (xcd & 1);
    const size_t row0 = (size_t)rb * 128;
    const int nbase = sp * ESPAN;

#define STAGE(DST, STEP) do {                                                           \
        const int snt_ = (STEP) >> 2, sch_ = (STEP) & 3;                                \
        _Pragma("unroll")                                                               \
        for (int i_ = 0; i_ < 4; ++i_) {                                                \
            int c_ = i_ * 256 + t;                                                      \
            int row_ = c_ >> 4, sl_ = c_ & 15;                                          \
            g2l16(eq + (size_t)(nbase + snt_ * NT + row_) * D + sch_ * KC + sl_ * 8,    \
                  (DST) + (size_t)(i_ * 256 + w * 64) * 8);                             \
        }                                                                               \
    } while (0)

    // prologue: first e-chunk -> LDS
    STAGE(es0, 0);

    // A fragments for this wave's 32 rows, full D, fused f32->f16
    f16x8 af[2][16];
#pragma unroll
    for (int mi = 0; mi < 2; ++mi) {
        const float4* xp = (const float4*)(x + (row0 + w * 32 + mi * 16 + l15) * D);
#pragma unroll
        for (int ks = 0; ks < 16; ++ks) {
            float4 p0 = xp[ks * 8 + l4 * 2];
            float4 p1 = xp[ks * 8 + l4 * 2 + 1];
            f16x8 v;
            v[0] = (_Float16)p0.x; v[1] = (_Float16)p0.y;
            v[2] = (_Float16)p0.z; v[3] = (_Float16)p0.w;
            v[4] = (_Float16)p1.x; v[5] = (_Float16)p1.y;
            v[6] = (_Float16)p1.z; v[7] = (_Float16)p1.w;
            af[mi][ks] = v;
        }
    }

    // -||e||^2/2 for tile 0 (prefetched per tile thereafter)
    float nnc[4];
#pragma unroll
    for (int ni = 0; ni < 4; ++ni) nnc[ni] = -0.5f * norms[nbase + ni * 16 + l15];

    // max-space top-2 trackers
    float v1[8], v2[8];
    int   i1[8], i2[8];
#pragma unroll
    for (int s = 0; s < 8; ++s) { v1[s] = v2[s] = -3.4e38f; i1[s] = i2[s] = 0x7fffffff; }

    unsigned short* cur = es0;
    unsigned short* nxt = es1;

    for (int nt_ = 0; nt_ < ESPAN / NT; ++nt_) {   // 32 entry tiles
        f32x4 acc[2][4];
#pragma unroll
        for (int mi = 0; mi < 2; ++mi)
#pragma unroll
            for (int ni = 0; ni < 4; ++ni) {
                float h = nnc[ni];
                acc[mi][ni] = (f32x4){h, h, h, h};
            }
        float nnn[4];

#pragma unroll
        for (int ch = 0; ch < 4; ++ch) {
            const int step = nt_ * 4 + ch;
            // cur-buffer loads were issued one full phase ago -> this wait is ~free
            asm volatile("s_waitcnt vmcnt(0)" ::: "memory");
            __builtin_amdgcn_s_barrier();
            __builtin_amdgcn_sched_barrier(0);   // nothing crosses the barrier
            if (step + 1 < NPHASE) STAGE(nxt, step + 1);   // prefetch flies over MFMA
            if (ch == 0 && nt_ + 1 < ESPAN / NT) {         // next tile's norms, hidden here
#pragma unroll
                for (int ni = 0; ni < 4; ++ni)
                    nnn[ni] = -0.5f * norms[nbase + (nt_ + 1) * NT + ni * 16 + l15];
            }
            __builtin_amdgcn_s_setprio(1);
            const char* esp = (const char*)cur;
            // 1-ahead fragment pipeline: caps frag live-range at 2x4 regs
            Frag4 fa, fb;
#pragma unroll
            for (int ni = 0; ni < 4; ++ni) {
                int slot = l4 ^ l15;                         // ksb = 0
                fa.v[ni] = *(const f16x8*)(esp + ni * 4096 + l15 * 256 + slot * 16);
            }
#pragma unroll
            for (int ksb = 0; ksb < 4; ++ksb) {
                if (ksb < 3) {
#pragma unroll
                    for (int ni = 0; ni < 4; ++ni) {
                        int slot = (((ksb + 1) << 2) | l4) ^ l15;
                        fb.v[ni] = *(const f16x8*)(esp + ni * 4096 + l15 * 256 + slot * 16);
                    }
                }
#pragma unroll
                for (int mi = 0; mi < 2; ++mi)
#pragma unroll
                    for (int ni = 0; ni < 4; ++ni)
                        acc[mi][ni] = __builtin_amdgcn_mfma_f32_16x16x32_f16(
                            af[mi][ch * 4 + ksb], fa.v[ni], acc[mi][ni], 0, 0, 0);
                if (ksb < 3) fa = fb;
            }
            __builtin_amdgcn_s_setprio(0);
            unsigned short* tswap = cur; cur = nxt; nxt = tswap;
        }

        // per-entry top-2 update in max-space (argmax acc == argmin dist)
        const int n0 = nbase + nt_ * NT;
#pragma unroll
        for (int mi = 0; mi < 2; ++mi)
#pragma unroll
            for (int r = 0; r < 4; ++r) {
                int s = mi * 4 + r;
#pragma unroll
                for (int ni = 0; ni < 4; ++ni) {
                    float a = acc[mi][ni][r];
                    int  cc = n0 + ni * 16 + l15;
                    if (a > v2[s]) {             // cc ascending -> strict > keeps lowest index on ties
                        bool b1 = a > v1[s];
                        v2[s] = b1 ? v1[s] : a; i2[s] = b1 ? i1[s] : cc;
                        v1[s] = b1 ? a : v1[s]; i1[s] = b1 ? cc : i1[s];
                    }
                }
            }
#pragma unroll
        for (int ni = 0; ni < 4; ++ni) nnc[ni] = nnn[ni];
    }
#undef STAGE

    // raw per-lane top-2 out (converted back to distance space: d = -2a)
#pragma unroll
    for (int s = 0; s < 8; ++s) {
        int mi = s >> 2, r = s & 3;
        size_t rowc = row0 + w * 32 + mi * 16 + l4 * 4 + r;
        cands[rowc * 64 + sp * 16 + l15] =
            make_float4(-2.f * v1[s], __int_as_float(i1[s]), -2.f * v2[s], __int_as_float(i2[s]));
    }
}

// ---------------- fused: merge cands + exact rescore + STE out + loss partials ----------------
__global__ __launch_bounds__(512)
void vq_finish(const float* __restrict__ x, const float* __restrict__ cb,
               const float* __restrict__ norms, const float4* __restrict__ cands,
               float* __restrict__ counts, float* __restrict__ psum, float* __restrict__ out) {
    __shared__ float red[8];
    const int t = threadIdx.x, w = t >> 6, lane = t & 63;
    const size_t row = (size_t)blockIdx.x * 8 + w;

    float4 c4 = cands[row * 64 + lane];
    float va = c4.x, vb = c4.z;
    int   ia = __float_as_int(c4.y), ib = __float_as_int(c4.w);
    float m = fminf(va, vb);
#pragma unroll
    for (int off = 1; off < 64; off <<= 1) m = fminf(m, __shfl_xor(m, off));
    const float thr = m + MARGIN;

    const float4* xp = (const float4*)(x + row * D);
    float4 xa = xp[lane * 2], xb = xp[lane * 2 + 1];

    float bd = 3.4e38f; int bi = 0x7fffffff;
#pragma unroll 1
    for (int q = 0; q < 2; ++q) {
        unsigned long long mk = __ballot((q == 0 ? va : vb) <= thr);
        while (mk) {
            int src = __builtin_ctzll(mk);
            mk &= mk - 1;
            int ci = __shfl(q == 0 ? ia : ib, src);
            const float4* ep = (const float4*)(cb + (size_t)ci * D);
            float4 ea = ep[lane * 2], eb = ep[lane * 2 + 1];
            float s = 0.f;
            s = fmaf(xa.x, ea.x, s); s = fmaf(xa.y, ea.y, s);
            s = fmaf(xa.z, ea.z, s); s = fmaf(xa.w, ea.w, s);
            s = fmaf(xb.x, eb.x, s); s = fmaf(xb.y, eb.y, s);
            s = fmaf(xb.z, eb.z, s); s = fmaf(xb.w, eb.w, s);
#pragma unroll
            for (int off = 1; off < 64; off <<= 1) s += __shfl_xor(s, off);
            float dd = fmaf(-2.f, s, norms[ci]);
            if (dd < bd || (dd == bd && ci < bi)) { bd = dd; bi = ci; }
        }
    }

    const float4* qp = (const float4*)(cb + (size_t)bi * D);
    float4 qa = qp[lane * 2], qb = qp[lane * 2 + 1];
    float4* op = (float4*)(out + row * D);
    float s2 = 0.f;
    float4 oa, ob;
    {
        float d0 = qa.x - xa.x; oa.x = xa.x + d0; s2 = fmaf(d0, d0, s2);
        float d1 = qa.y - xa.y; oa.y = xa.y + d1; s2 = fmaf(d1, d1, s2);
        float d2 = qa.z - xa.z; oa.z = xa.z + d2; s2 = fmaf(d2, d2, s2);
        float d3 = qa.w - xa.w; oa.w = xa.w + d3; s2 = fmaf(d3, d3, s2);
        float d4 = qb.x - xb.x; ob.x = xb.x + d4; s2 = fmaf(d4, d4, s2);
        float d5 = qb.y - xb.y; ob.y = xb.y + d5; s2 = fmaf(d5, d5, s2);
        float d6 = qb.z - xb.z; ob.z = xb.z + d6; s2 = fmaf(d6, d6, s2);
        float d7 = qb.w - xb.w; ob.w = xb.w + d7; s2 = fmaf(d7, d7, s2);
    }
    op[lane * 2] = oa; op[lane * 2 + 1] = ob;
    for (int off = 32; off; off >>= 1) s2 += __shfl_down(s2, off);
    if (lane == 0) {
        red[w] = s2;
        atomicAdd(&counts[bi], 1.0f);
    }
    __syncthreads();
    if (t == 0) {
        float s = 0.f;
#pragma unroll
        for (int i = 0; i < 8; ++i) s += red[i];
        psum[blockIdx.x] = s;
    }
}

// ---------------- loss + perplexity ----------------
__global__ void vq_finalize_kernel(const float* __restrict__ counts, const float* __restrict__ psum,
                                   float* __restrict__ out2) {
    __shared__ float rede[256];
    __shared__ float reds[256];
    float se = 0.f, ss = 0.f;
    for (int i = threadIdx.x; i < NE; i += 256) {
        float p = counts[i] * (1.0f / (float)BATCH);
        se += p * logf(p + 1e-10f);
    }
    for (int i = threadIdx.x; i < 4096; i += 256) ss += psum[i];
    rede[threadIdx.x] = se; reds[threadIdx.x] = ss;
    __syncthreads();
    for (int off = 128; off; off >>= 1) {
        if (threadIdx.x < off) {
            rede[threadIdx.x] += rede[threadIdx.x + off];
            reds[threadIdx.x] += reds[threadIdx.x + off];
        }
        __syncthreads();
    }
    if (threadIdx.x == 0) {
        out2[0] = 1.25f * reds[0] * (1.0f / (float)((size_t)BATCH * D));
        out2[1] = expf(-rede[0]);
    }
}

// ---------------- fallback fp32 path (round-1, known-good) ----------------
__global__ void vq_norms_kernel(const float* __restrict__ cb, float* __restrict__ norms) {
    int row  = blockIdx.x * 4 + (threadIdx.x >> 6);
    int lane = threadIdx.x & 63;
    const float4* p = (const float4*)(cb + (size_t)row * D);
    float s = 0.f;
#pragma unroll
    for (int i = 0; i < 2; ++i) {
        float4 v = p[lane + 64 * i];
        s += v.x * v.x + v.y * v.y + v.z * v.z + v.w * v.w;
    }
    for (int off = 32; off; off >>= 1) s += __shfl_down(s, off);
    if (lane == 0) norms[row] = s;
}

#define BM 64
#define BN 64
#define BK 16
#define LDSP 68
__global__ __launch_bounds__(256)
void vq_argmin_kernel(const float* __restrict__ x, const float* __restrict__ cb,
                      const float* __restrict__ norms, int* __restrict__ out_idx) {
    __shared__ float xs[BK * LDSP];
    __shared__ float es[BK * LDSP];
    __shared__ float rv[BM][16];
    __shared__ int   ri[BM][16];
    const int t = threadIdx.x, tx = t & 15, ty = t >> 4;
    const int row0 = blockIdx.x * BM, ldrow = t >> 2, ldq = t & 3;
    float minv[4]; int mini[4];
#pragma unroll
    for (int i = 0; i < 4; ++i) { minv[i] = 3.4e38f; mini[i] = 0; }
    for (int n0 = 0; n0 < NE; n0 += BN) {
        float acc[4][4];
#pragma unroll
        for (int i = 0; i < 4; ++i)
#pragma unroll
            for (int j = 0; j < 4; ++j) acc[i][j] = 0.f;
        for (int kk = 0; kk < D; kk += BK) {
            __syncthreads();
            float4 xv = *(const float4*)&x [(size_t)(row0 + ldrow) * D + kk + ldq * 4];
            float4 ev = *(const float4*)&cb[(size_t)(n0   + ldrow) * D + kk + ldq * 4];
            const float* xvp = (const float*)&xv;
            const float* evp = (const float*)&ev;
#pragma unroll
            for (int j = 0; j < 4; ++j) {
                xs[(ldq * 4 + j) * LDSP + ldrow] = xvp[j];
                es[(ldq * 4 + j) * LDSP + ldrow] = evp[j];
            }
            __syncthreads();
#pragma unroll
            for (int k = 0; k < BK; ++k) {
                float4 xr4 = *(const float4*)&xs[k * LDSP + ty * 4];
                float4 er4 = *(const float4*)&es[k * LDSP + tx * 4];
                const float xr[4] = {xr4.x, xr4.y, xr4.z, xr4.w};
                const float er[4] = {er4.x, er4.y, er4.z, er4.w};
#pragma unroll
                for (int i = 0; i < 4; ++i)
#pragma unroll
                    for (int j = 0; j < 4; ++j)
                        acc[i][j] = fmaf(xr[i], er[j], acc[i][j]);
            }
        }
#pragma unroll
        for (int j = 0; j < 4; ++j) {
            int n = n0 + tx * 4 + j;
            float nnv = norms[n];
#pragma unroll
            for (int i = 0; i < 4; ++i) {
                float dd = fmaf(-2.f, acc[i][j], nnv);
                if (dd < minv[i]) { minv[i] = dd; mini[i] = n; }
            }
        }
    }
    __syncthreads();
#pragma unroll
    for (int i = 0; i < 4; ++i) { rv[ty * 4 + i][tx] = minv[i]; ri[ty * 4 + i][tx] = mini[i]; }
    __syncthreads();
    if (t < BM) {
        float bv = rv[t][0]; int bi = ri[t][0];
#pragma unroll
        for (int j = 1; j < 16; ++j) {
            float v = rv[t][j]; int iz = ri[t][j];
            if (v < bv || (v == bv && iz < bi)) { bv = v; bi = iz; }
        }
        out_idx[row0 + t] = bi;
    }
}

__global__ void vq_gather_kernel(const float* __restrict__ x, const float* __restrict__ cb,
                                 const int* __restrict__ idx, float* __restrict__ out,
                                 float* __restrict__ counts, float* __restrict__ psum) {
    const int b = blockIdx.x, lane = threadIdx.x;
    const int e = idx[b];
    const float4* xp = (const float4*)(x  + (size_t)b * D);
    const float4* qp = (const float4*)(cb + (size_t)e * D);
    float4*       op = (float4*)(out + (size_t)b * D);
    float s = 0.f;
#pragma unroll
    for (int i = 0; i < 2; ++i) {
        float4 xv = xp[lane + 64 * i];
        float4 qv = qp[lane + 64 * i];
        float4 ov;
        float dx = qv.x - xv.x; ov.x = xv.x + dx; s = fmaf(dx, dx, s);
        float dy = qv.y - xv.y; ov.y = xv.y + dy; s = fmaf(dy, dy, s);
        float dz = qv.z - xv.z; ov.z = xv.z + dz; s = fmaf(dz, dz, s);
        float dw = qv.w - xv.w; ov.w = xv.w + dw; s = fmaf(dw, dw, s);
        op[lane + 64 * i] = ov;
    }
    for (int off = 32; off; off >>= 1) s += __shfl_down(s, off);
    if (lane == 0) {
        atomicAdd(&psum[0], s);
        atomicAdd(&counts[e], 1.0f);
    }
}

extern "C" void kernel_launch(void* const* d_in, const int* in_sizes, int n_in,
                              void* d_out, int out_size, void* d_ws, size_t ws_size,
                              hipStream_t stream) {
    const float* x  = (const float*)d_in[0];
    const float* cb = (const float*)d_in[1];
    float* out = (float*)d_out;

    char* ws = (char*)d_ws;
    float*  norms  = (float*)ws;                             // 32 KB @ 0
    float*  counts = (float*)(ws + 32768);                   // 32 KB
    float*  psum   = (float*)(ws + 65536);                   // 16 KB (4096 partials)
    int*    idx    = (int*)(ws + 81920);                     // 128 KB (fallback only)
    float4* cands  = (float4*)(ws + 262144);                 // 32 MB (32768 x 64 x 16B)
    unsigned short* eq = (unsigned short*)(ws + 33816576);   // 8 MB fp16 swizzled codebook
    const size_t WS_NEED = 42205184;

    hipMemsetAsync(counts, 0, NE * sizeof(float), stream);

    if (ws_size >= WS_NEED) {
        vq_prep<<<NE / 4, 256, 0, stream>>>(cb, eq, norms);
        vq_topk2<<<1024, 256, 0, stream>>>(x, eq, norms, cands);
        vq_finish<<<BATCH / 8, 512, 0, stream>>>(x, cb, norms, cands, counts, psum, out);
    } else {
        hipMemsetAsync(psum, 0, 4096 * sizeof(float), stream);
        vq_norms_kernel<<<NE / 4, 256, 0, stream>>>(cb, norms);
        vq_argmin_kernel<<<BATCH / BM, 256, 0, stream>>>(x, cb, norms, idx);
        vq_gather_kernel<<<BATCH, 64, 0, stream>>>(x, cb, idx, out, counts, psum);
    }
    vq_finalize_kernel<<<1, 256, 0, stream>>>(counts, psum, out + (size_t)BATCH * D);
}